// Round 2
// baseline (5063.480 us; speedup 1.0000x reference)
//
#include <hip/hip_runtime.h>

#define NN 10000
#define EE 160000
#define DD 512
#define EDIM 128
#define LLAYERS 3
#define LN_EPS 1e-5f

// ---------------- edge kernel ----------------
// Computes m = relu(h[src] + edge_attr @ We + be) and atomically accumulates
// into agg[dst]. Block tile: 32 edges x 128 cols, K=128. Block = 256 threads.
// grid = (E/32, 512/128)
__global__ __launch_bounds__(256) void edge_kernel(
    const float* __restrict__ h,
    const float* __restrict__ edge_attr,
    const float* __restrict__ We,    // [128][512] (layer slice)
    const float* __restrict__ be,    // [512]
    const int* __restrict__ srcv,    // int32! harness converts int inputs to int32
    const int* __restrict__ dstv,
    float* __restrict__ agg)
{
    __shared__ float sA[EDIM][36];   // [k][edge] transposed, pad->36 (16B-aligned float4 rows)
    __shared__ float sB[32][128];    // [k-chunk][col]

    const int tid = threadIdx.x;
    const int tx = tid & 31;         // col group: cols c0 + tx*4 .. +3
    const int ty = tid >> 5;         // edge group: edges ty*4 .. +3
    const int e0 = blockIdx.x * 32;
    const int c0 = blockIdx.y * 128;

    // stage edge_attr tile (32 edges x 128 k), transposed into sA
    const float* ea = edge_attr + (size_t)e0 * EDIM;
    for (int i = tid; i < 32 * EDIM; i += 256) {
        int e = i >> 7;          // i / 128
        int k = i & 127;
        sA[k][e] = ea[i];
    }

    float4 acc[4];
    #pragma unroll
    for (int r = 0; r < 4; r++) acc[r] = make_float4(0.f, 0.f, 0.f, 0.f);

    for (int kc = 0; kc < EDIM; kc += 32) {
        __syncthreads();  // protect sB (and first-iter sA) before restage
        for (int i = tid; i < 32 * 128; i += 256) {
            int k = i >> 7;
            int c = i & 127;
            sB[k][c] = We[(size_t)(kc + k) * DD + c0 + c];
        }
        __syncthreads();
        #pragma unroll
        for (int kk = 0; kk < 32; kk++) {
            float4 b = *(const float4*)&sB[kk][tx * 4];
            float4 a = *(const float4*)&sA[kc + kk][ty * 4];
            acc[0].x += a.x * b.x; acc[0].y += a.x * b.y; acc[0].z += a.x * b.z; acc[0].w += a.x * b.w;
            acc[1].x += a.y * b.x; acc[1].y += a.y * b.y; acc[1].z += a.y * b.z; acc[1].w += a.y * b.w;
            acc[2].x += a.z * b.x; acc[2].y += a.z * b.y; acc[2].z += a.z * b.z; acc[2].w += a.z * b.w;
            acc[3].x += a.w * b.x; acc[3].y += a.w * b.y; acc[3].z += a.w * b.z; acc[3].w += a.w * b.w;
        }
    }

    const float4 bev = *(const float4*)&be[c0 + tx * 4];
    #pragma unroll
    for (int es = 0; es < 4; es++) {
        int e = e0 + ty * 4 + es;
        int s = srcv[e];
        int d = dstv[e];
        const float4 hv = *(const float4*)&h[(size_t)s * DD + c0 + tx * 4];
        float mx = fmaxf(acc[es].x + hv.x + bev.x, 0.f);
        float my = fmaxf(acc[es].y + hv.y + bev.y, 0.f);
        float mz = fmaxf(acc[es].z + hv.z + bev.z, 0.f);
        float mw = fmaxf(acc[es].w + hv.w + bev.w, 0.f);
        float* ap = &agg[(size_t)d * DD + c0 + tx * 4];
        atomicAdd(ap + 0, mx);
        atomicAdd(ap + 1, my);
        atomicAdd(ap + 2, mz);
        atomicAdd(ap + 3, mw);
    }
}

// ---------------- node GEMM ----------------
// C[M,512] = act(A[M,512] @ W[512,512] + bias). Block tile 64 rows x 128 cols,
// per-thread 8x4. grid = (ceil(M/64), 4), block 256.
template <bool RELU>
__global__ __launch_bounds__(256) void gemm_kernel(
    const float* __restrict__ A,
    const float* __restrict__ W,
    const float* __restrict__ bias,
    float* __restrict__ C,
    int M)
{
    __shared__ float sAt[32][68];   // [k][m] transposed, pad->68
    __shared__ float sB[32][128];

    const int tid = threadIdx.x;
    const int tx = tid & 31;        // cols c0 + tx*4
    const int ty = tid >> 5;        // rows m0 + ty*8 .. +7
    const int m0 = blockIdx.x * 64;
    const int c0 = blockIdx.y * 128;

    float4 acc[8];
    #pragma unroll
    for (int r = 0; r < 8; r++) acc[r] = make_float4(0.f, 0.f, 0.f, 0.f);

    for (int kc = 0; kc < DD; kc += 32) {
        __syncthreads();
        for (int i = tid; i < 64 * 32; i += 256) {
            int m = i >> 5;
            int k = i & 31;
            int gm = m0 + m;
            sAt[k][m] = (gm < M) ? A[(size_t)gm * DD + kc + k] : 0.f;
        }
        for (int i = tid; i < 32 * 128; i += 256) {
            int k = i >> 7;
            int c = i & 127;
            sB[k][c] = W[(size_t)(kc + k) * DD + c0 + c];
        }
        __syncthreads();
        #pragma unroll
        for (int kk = 0; kk < 32; kk++) {
            float4 b  = *(const float4*)&sB[kk][tx * 4];
            float4 a0 = *(const float4*)&sAt[kk][ty * 8];
            float4 a1 = *(const float4*)&sAt[kk][ty * 8 + 4];
            acc[0].x += a0.x * b.x; acc[0].y += a0.x * b.y; acc[0].z += a0.x * b.z; acc[0].w += a0.x * b.w;
            acc[1].x += a0.y * b.x; acc[1].y += a0.y * b.y; acc[1].z += a0.y * b.z; acc[1].w += a0.y * b.w;
            acc[2].x += a0.z * b.x; acc[2].y += a0.z * b.y; acc[2].z += a0.z * b.z; acc[2].w += a0.z * b.w;
            acc[3].x += a0.w * b.x; acc[3].y += a0.w * b.y; acc[3].z += a0.w * b.z; acc[3].w += a0.w * b.w;
            acc[4].x += a1.x * b.x; acc[4].y += a1.x * b.y; acc[4].z += a1.x * b.z; acc[4].w += a1.x * b.w;
            acc[5].x += a1.y * b.x; acc[5].y += a1.y * b.y; acc[5].z += a1.y * b.z; acc[5].w += a1.y * b.w;
            acc[6].x += a1.z * b.x; acc[6].y += a1.z * b.y; acc[6].z += a1.z * b.z; acc[6].w += a1.z * b.w;
            acc[7].x += a1.w * b.x; acc[7].y += a1.w * b.y; acc[7].z += a1.w * b.z; acc[7].w += a1.w * b.w;
        }
    }

    const float4 bv = *(const float4*)&bias[c0 + tx * 4];
    #pragma unroll
    for (int r = 0; r < 8; r++) {
        int gm = m0 + ty * 8 + r;
        if (gm < M) {
            float4 v;
            v.x = acc[r].x + bv.x;
            v.y = acc[r].y + bv.y;
            v.z = acc[r].z + bv.z;
            v.w = acc[r].w + bv.w;
            if (RELU) {
                v.x = fmaxf(v.x, 0.f); v.y = fmaxf(v.y, 0.f);
                v.z = fmaxf(v.z, 0.f); v.w = fmaxf(v.w, 0.f);
            }
            *(float4*)&C[(size_t)gm * DD + c0 + tx * 4] = v;
        }
    }
}

// ---------------- g = (1+eps)*h + agg ----------------
__global__ __launch_bounds__(256) void axpb_kernel(
    const float* __restrict__ h, const float* __restrict__ agg,
    const float* __restrict__ eps_p, float* __restrict__ g)
{
    int i = blockIdx.x * 256 + threadIdx.x;   // float4 index, exact grid
    float s = 1.0f + eps_p[0];
    const float4 hv = ((const float4*)h)[i];
    const float4 av = ((const float4*)agg)[i];
    float4 o;
    o.x = s * hv.x + av.x;
    o.y = s * hv.y + av.y;
    o.z = s * hv.z + av.z;
    o.w = s * hv.w + av.w;
    ((float4*)g)[i] = o;
}

// ---------------- fused ReLU + LayerNorm ----------------
// one block (256 thr) per row; each thread handles cols tid and tid+256
__global__ __launch_bounds__(256) void relu_ln_kernel(
    const float* __restrict__ g2,
    const float* __restrict__ gamma,
    const float* __restrict__ beta,
    float* __restrict__ hout)
{
    __shared__ float ss[4], ssq[4];
    const int row = blockIdx.x;
    const int tid = threadIdx.x;
    const float* gr = g2 + (size_t)row * DD;

    float v0 = fmaxf(gr[tid], 0.f);
    float v1 = fmaxf(gr[tid + 256], 0.f);
    float s  = v0 + v1;
    float sq = v0 * v0 + v1 * v1;
    #pragma unroll
    for (int off = 32; off > 0; off >>= 1) {
        s  += __shfl_down(s, off);
        sq += __shfl_down(sq, off);
    }
    const int wave = tid >> 6;
    const int lane = tid & 63;
    if (lane == 0) { ss[wave] = s; ssq[wave] = sq; }
    __syncthreads();
    if (tid == 0) {
        float S  = ss[0] + ss[1] + ss[2] + ss[3];
        float SQ = ssq[0] + ssq[1] + ssq[2] + ssq[3];
        float mu = S * (1.f / 512.f);
        float var = SQ * (1.f / 512.f) - mu * mu;
        ss[0]  = mu;
        ssq[0] = rsqrtf(var + LN_EPS);
    }
    __syncthreads();
    float mu = ss[0], rstd = ssq[0];
    hout[(size_t)row * DD + tid]       = (v0 - mu) * rstd * gamma[tid] + beta[tid];
    hout[(size_t)row * DD + tid + 256] = (v1 - mu) * rstd * gamma[tid + 256] + beta[tid + 256];
}

extern "C" void kernel_launch(void* const* d_in, const int* in_sizes, int n_in,
                              void* d_out, int out_size, void* d_ws, size_t ws_size,
                              hipStream_t stream)
{
    (void)in_sizes; (void)n_in; (void)out_size; (void)ws_size;

    const float* x          = (const float*)d_in[0];
    const int*   edge_index = (const int*)d_in[1];   // int32 per harness contract
    const float* edge_attr  = (const float*)d_in[2];
    const float* We         = (const float*)d_in[3];
    const float* be         = (const float*)d_in[4];
    const float* eps        = (const float*)d_in[5];
    const float* W1         = (const float*)d_in[6];
    const float* b1         = (const float*)d_in[7];
    const float* W2         = (const float*)d_in[8];
    const float* b2         = (const float*)d_in[9];
    const float* gamma      = (const float*)d_in[10];
    const float* beta       = (const float*)d_in[11];
    const float* Wf         = (const float*)d_in[12];
    const float* bf         = (const float*)d_in[13];

    float* h   = (float*)d_ws;                      // [N,512]
    float* agg = h + (size_t)NN * DD;               // [N,512]; reused as t1
    float* g   = (float*)d_out;                     // [N,512] scratch; final out

    const int* srcv = edge_index;
    const int* dstv = edge_index + EE;

    hipMemcpyAsync(h, x, (size_t)NN * DD * sizeof(float),
                   hipMemcpyDeviceToDevice, stream);

    dim3 eblk(256), egrid(EE / 32, DD / 128);
    dim3 gblk(256), ggrid((NN + 63) / 64, DD / 128);

    for (int l = 0; l < LLAYERS; l++) {
        hipMemsetAsync(agg, 0, (size_t)NN * DD * sizeof(float), stream);
        edge_kernel<<<egrid, eblk, 0, stream>>>(
            h, edge_attr, We + (size_t)l * EDIM * DD, be + (size_t)l * DD,
            srcv, dstv, agg);
        axpb_kernel<<<dim3(NN * DD / 4 / 256), 256, 0, stream>>>(h, agg, eps + l, g);
        gemm_kernel<true><<<ggrid, gblk, 0, stream>>>(
            g, W1 + (size_t)l * DD * DD, b1 + (size_t)l * DD, agg /*t1*/, NN);
        gemm_kernel<false><<<ggrid, gblk, 0, stream>>>(
            agg, W2 + (size_t)l * DD * DD, b2 + (size_t)l * DD, g, NN);
        relu_ln_kernel<<<dim3(NN), 256, 0, stream>>>(
            g, gamma + (size_t)l * DD, beta + (size_t)l * DD, h);
    }
    gemm_kernel<false><<<ggrid, gblk, 0, stream>>>(h, Wf, bf, (float*)d_out, NN);
}

// Round 3
// 3795.622 us; speedup vs baseline: 1.3340x; 1.3340x over previous
//
#include <hip/hip_runtime.h>

#define NN 10000
#define EE 160000
#define DD 512
#define EDIM 128
#define LLAYERS 3
#define LN_EPS 1e-5f

// ---------------- CSR build: counting sort of edges by dst ----------------
__global__ __launch_bounds__(256) void hist_kernel(
    const int* __restrict__ dstv, int* __restrict__ deg)
{
    int e = blockIdx.x * 256 + threadIdx.x;
    if (e < EE) atomicAdd(&deg[dstv[e]], 1);
}

// single block, 256 threads: exclusive scan of deg[0..NN) -> base, cursor
__global__ __launch_bounds__(256) void scan_kernel(
    const int* __restrict__ deg, int* __restrict__ base, int* __restrict__ cursor)
{
    __shared__ int sums[256];
    const int t = threadIdx.x;
    const int CH = 40;                       // 256*40 = 10240 >= NN
    int lo = t * CH;
    int hi = lo + CH; if (hi > NN) hi = NN;
    int s = 0;
    for (int i = lo; i < hi; i++) s += deg[i];
    sums[t] = s;
    __syncthreads();
    for (int off = 1; off < 256; off <<= 1) {
        int v = (t >= off) ? sums[t - off] : 0;
        __syncthreads();
        sums[t] += v;
        __syncthreads();
    }
    int run = (t == 0) ? 0 : sums[t - 1];
    for (int i = lo; i < hi; i++) {
        base[i] = run; cursor[i] = run;
        run += deg[i];
    }
}

__global__ __launch_bounds__(256) void scatter_kernel(
    const int* __restrict__ srcv, const int* __restrict__ dstv,
    int* __restrict__ cursor,
    int* __restrict__ ssrc, int* __restrict__ sdst, int* __restrict__ perm)
{
    int e = blockIdx.x * 256 + threadIdx.x;
    if (e < EE) {
        int d = dstv[e];
        int pos = atomicAdd(&cursor[d], 1);
        ssrc[pos] = srcv[e];
        sdst[pos] = d;
        perm[pos] = e;
    }
}

// ---------------- edge kernel (dst-sorted) ----------------
// m = relu(h[src] + edge_attr @ We + be), accumulate into agg[dst].
// Edges arrive sorted by dst: combine same-dst runs in registers, and the
// residual atomics from neighboring blocks hit hot L2 lines.
// Block tile: 32 edges x 128 cols, K=128. grid = (E/32, 512/128), block 256.
__global__ __launch_bounds__(256) void edge_kernel(
    const float* __restrict__ h,
    const float* __restrict__ edge_attr,
    const float* __restrict__ We,    // [128][512] (layer slice)
    const float* __restrict__ be,    // [512]
    const int* __restrict__ ssrc,    // sorted by dst
    const int* __restrict__ sdst,
    const int* __restrict__ perm,    // sorted slot -> original edge id
    float* __restrict__ agg)
{
    __shared__ float sA[EDIM][36];   // [k][edge] transposed, pad->36
    __shared__ float sB[32][128];    // [k-chunk][col]

    const int tid = threadIdx.x;
    const int tx = tid & 31;         // col group: cols c0 + tx*4 .. +3
    const int ty = tid >> 5;         // edge group: edges ty*4 .. +3
    const int e0 = blockIdx.x * 32;
    const int c0 = blockIdx.y * 128;

    // stage edge_attr tile (32 edges x 128 k) via perm, transposed into sA
    for (int i = tid; i < 32 * EDIM; i += 256) {
        int e = i >> 7;          // i / 128
        int k = i & 127;
        sA[k][e] = edge_attr[(size_t)perm[e0 + e] * EDIM + k];
    }

    float4 acc[4];
    #pragma unroll
    for (int r = 0; r < 4; r++) acc[r] = make_float4(0.f, 0.f, 0.f, 0.f);

    for (int kc = 0; kc < EDIM; kc += 32) {
        __syncthreads();
        for (int i = tid; i < 32 * 128; i += 256) {
            int k = i >> 7;
            int c = i & 127;
            sB[k][c] = We[(size_t)(kc + k) * DD + c0 + c];
        }
        __syncthreads();
        #pragma unroll
        for (int kk = 0; kk < 32; kk++) {
            float4 b = *(const float4*)&sB[kk][tx * 4];
            float4 a = *(const float4*)&sA[kc + kk][ty * 4];
            acc[0].x += a.x * b.x; acc[0].y += a.x * b.y; acc[0].z += a.x * b.z; acc[0].w += a.x * b.w;
            acc[1].x += a.y * b.x; acc[1].y += a.y * b.y; acc[1].z += a.y * b.z; acc[1].w += a.y * b.w;
            acc[2].x += a.z * b.x; acc[2].y += a.z * b.y; acc[2].z += a.z * b.z; acc[2].w += a.z * b.w;
            acc[3].x += a.w * b.x; acc[3].y += a.w * b.y; acc[3].z += a.w * b.z; acc[3].w += a.w * b.w;
        }
    }

    const float4 bev = *(const float4*)&be[c0 + tx * 4];

    // messages for this thread's 4 (sorted) edges
    float4 m[4];
    int    d[4];
    #pragma unroll
    for (int es = 0; es < 4; es++) {
        int e = e0 + ty * 4 + es;
        int s = ssrc[e];
        d[es] = sdst[e];
        const float4 hv = *(const float4*)&h[(size_t)s * DD + c0 + tx * 4];
        m[es].x = fmaxf(acc[es].x + hv.x + bev.x, 0.f);
        m[es].y = fmaxf(acc[es].y + hv.y + bev.y, 0.f);
        m[es].z = fmaxf(acc[es].z + hv.z + bev.z, 0.f);
        m[es].w = fmaxf(acc[es].w + hv.w + bev.w, 0.f);
    }

    // combine same-dst runs, one atomic flush per run
    float4 run = m[0];
    int    rd  = d[0];
    #pragma unroll
    for (int es = 1; es < 4; es++) {
        if (d[es] == rd) {
            run.x += m[es].x; run.y += m[es].y; run.z += m[es].z; run.w += m[es].w;
        } else {
            float* ap = &agg[(size_t)rd * DD + c0 + tx * 4];
            atomicAdd(ap + 0, run.x);
            atomicAdd(ap + 1, run.y);
            atomicAdd(ap + 2, run.z);
            atomicAdd(ap + 3, run.w);
            run = m[es]; rd = d[es];
        }
    }
    float* ap = &agg[(size_t)rd * DD + c0 + tx * 4];
    atomicAdd(ap + 0, run.x);
    atomicAdd(ap + 1, run.y);
    atomicAdd(ap + 2, run.z);
    atomicAdd(ap + 3, run.w);
}

// ---------------- node GEMM ----------------
// C[M,512] = act(A[M,512] @ W[512,512] + bias). Block tile 64x128,
// per-thread 8x4. grid = (ceil(M/64), 4), block 256.
template <bool RELU>
__global__ __launch_bounds__(256) void gemm_kernel(
    const float* __restrict__ A,
    const float* __restrict__ W,
    const float* __restrict__ bias,
    float* __restrict__ C,
    int M)
{
    __shared__ float sAt[32][68];
    __shared__ float sB[32][128];

    const int tid = threadIdx.x;
    const int tx = tid & 31;
    const int ty = tid >> 5;
    const int m0 = blockIdx.x * 64;
    const int c0 = blockIdx.y * 128;

    float4 acc[8];
    #pragma unroll
    for (int r = 0; r < 8; r++) acc[r] = make_float4(0.f, 0.f, 0.f, 0.f);

    for (int kc = 0; kc < DD; kc += 32) {
        __syncthreads();
        for (int i = tid; i < 64 * 32; i += 256) {
            int m = i >> 5;
            int k = i & 31;
            int gm = m0 + m;
            sAt[k][m] = (gm < M) ? A[(size_t)gm * DD + kc + k] : 0.f;
        }
        for (int i = tid; i < 32 * 128; i += 256) {
            int k = i >> 7;
            int c = i & 127;
            sB[k][c] = W[(size_t)(kc + k) * DD + c0 + c];
        }
        __syncthreads();
        #pragma unroll
        for (int kk = 0; kk < 32; kk++) {
            float4 b  = *(const float4*)&sB[kk][tx * 4];
            float4 a0 = *(const float4*)&sAt[kk][ty * 8];
            float4 a1 = *(const float4*)&sAt[kk][ty * 8 + 4];
            acc[0].x += a0.x * b.x; acc[0].y += a0.x * b.y; acc[0].z += a0.x * b.z; acc[0].w += a0.x * b.w;
            acc[1].x += a0.y * b.x; acc[1].y += a0.y * b.y; acc[1].z += a0.y * b.z; acc[1].w += a0.y * b.w;
            acc[2].x += a0.z * b.x; acc[2].y += a0.z * b.y; acc[2].z += a0.z * b.z; acc[2].w += a0.z * b.w;
            acc[3].x += a0.w * b.x; acc[3].y += a0.w * b.y; acc[3].z += a0.w * b.z; acc[3].w += a0.w * b.w;
            acc[4].x += a1.x * b.x; acc[4].y += a1.x * b.y; acc[4].z += a1.x * b.z; acc[4].w += a1.x * b.w;
            acc[5].x += a1.y * b.x; acc[5].y += a1.y * b.y; acc[5].z += a1.y * b.z; acc[5].w += a1.y * b.w;
            acc[6].x += a1.z * b.x; acc[6].y += a1.z * b.y; acc[6].z += a1.z * b.z; acc[6].w += a1.z * b.w;
            acc[7].x += a1.w * b.x; acc[7].y += a1.w * b.y; acc[7].z += a1.w * b.z; acc[7].w += a1.w * b.w;
        }
    }

    const float4 bv = *(const float4*)&bias[c0 + tx * 4];
    #pragma unroll
    for (int r = 0; r < 8; r++) {
        int gm = m0 + ty * 8 + r;
        if (gm < M) {
            float4 v;
            v.x = acc[r].x + bv.x;
            v.y = acc[r].y + bv.y;
            v.z = acc[r].z + bv.z;
            v.w = acc[r].w + bv.w;
            if (RELU) {
                v.x = fmaxf(v.x, 0.f); v.y = fmaxf(v.y, 0.f);
                v.z = fmaxf(v.z, 0.f); v.w = fmaxf(v.w, 0.f);
            }
            *(float4*)&C[(size_t)gm * DD + c0 + tx * 4] = v;
        }
    }
}

// ---------------- g = (1+eps)*h + agg ----------------
__global__ __launch_bounds__(256) void axpb_kernel(
    const float* __restrict__ h, const float* __restrict__ agg,
    const float* __restrict__ eps_p, float* __restrict__ g)
{
    int i = blockIdx.x * 256 + threadIdx.x;
    float s = 1.0f + eps_p[0];
    const float4 hv = ((const float4*)h)[i];
    const float4 av = ((const float4*)agg)[i];
    float4 o;
    o.x = s * hv.x + av.x;
    o.y = s * hv.y + av.y;
    o.z = s * hv.z + av.z;
    o.w = s * hv.w + av.w;
    ((float4*)g)[i] = o;
}

// ---------------- fused ReLU + LayerNorm ----------------
__global__ __launch_bounds__(256) void relu_ln_kernel(
    const float* __restrict__ g2,
    const float* __restrict__ gamma,
    const float* __restrict__ beta,
    float* __restrict__ hout)
{
    __shared__ float ss[4], ssq[4];
    const int row = blockIdx.x;
    const int tid = threadIdx.x;
    const float* gr = g2 + (size_t)row * DD;

    float v0 = fmaxf(gr[tid], 0.f);
    float v1 = fmaxf(gr[tid + 256], 0.f);
    float s  = v0 + v1;
    float sq = v0 * v0 + v1 * v1;
    #pragma unroll
    for (int off = 32; off > 0; off >>= 1) {
        s  += __shfl_down(s, off);
        sq += __shfl_down(sq, off);
    }
    const int wave = tid >> 6;
    const int lane = tid & 63;
    if (lane == 0) { ss[wave] = s; ssq[wave] = sq; }
    __syncthreads();
    if (tid == 0) {
        float S  = ss[0] + ss[1] + ss[2] + ss[3];
        float SQ = ssq[0] + ssq[1] + ssq[2] + ssq[3];
        float mu = S * (1.f / 512.f);
        float var = SQ * (1.f / 512.f) - mu * mu;
        ss[0]  = mu;
        ssq[0] = rsqrtf(var + LN_EPS);
    }
    __syncthreads();
    float mu = ss[0], rstd = ssq[0];
    hout[(size_t)row * DD + tid]       = (v0 - mu) * rstd * gamma[tid] + beta[tid];
    hout[(size_t)row * DD + tid + 256] = (v1 - mu) * rstd * gamma[tid + 256] + beta[tid + 256];
}

extern "C" void kernel_launch(void* const* d_in, const int* in_sizes, int n_in,
                              void* d_out, int out_size, void* d_ws, size_t ws_size,
                              hipStream_t stream)
{
    (void)in_sizes; (void)n_in; (void)out_size; (void)ws_size;

    const float* x          = (const float*)d_in[0];
    const int*   edge_index = (const int*)d_in[1];   // int32 per harness contract
    const float* edge_attr  = (const float*)d_in[2];
    const float* We         = (const float*)d_in[3];
    const float* be         = (const float*)d_in[4];
    const float* eps        = (const float*)d_in[5];
    const float* W1         = (const float*)d_in[6];
    const float* b1         = (const float*)d_in[7];
    const float* W2         = (const float*)d_in[8];
    const float* b2         = (const float*)d_in[9];
    const float* gamma      = (const float*)d_in[10];
    const float* beta       = (const float*)d_in[11];
    const float* Wf         = (const float*)d_in[12];
    const float* bf         = (const float*)d_in[13];

    // workspace layout
    float* h    = (float*)d_ws;                        // [N,512]
    float* agg  = h + (size_t)NN * DD;                 // [N,512]; reused as t1
    int*   deg    = (int*)(agg + (size_t)NN * DD);     // [N]
    int*   base   = deg + NN;                          // [N]
    int*   cursor = base + NN;                         // [N]
    int*   ssrc   = cursor + NN;                       // [E]
    int*   sdst   = ssrc + EE;                         // [E]
    int*   perm   = sdst + EE;                         // [E]
    float* g    = (float*)d_out;                       // [N,512] scratch; final out

    const int* srcv = edge_index;
    const int* dstv = edge_index + EE;

    hipMemcpyAsync(h, x, (size_t)NN * DD * sizeof(float),
                   hipMemcpyDeviceToDevice, stream);

    // ---- build dst-sorted edge order (once; reused by all 3 layers) ----
    hipMemsetAsync(deg, 0, NN * sizeof(int), stream);
    hist_kernel<<<dim3((EE + 255) / 256), 256, 0, stream>>>(dstv, deg);
    scan_kernel<<<dim3(1), 256, 0, stream>>>(deg, base, cursor);
    scatter_kernel<<<dim3((EE + 255) / 256), 256, 0, stream>>>(
        srcv, dstv, cursor, ssrc, sdst, perm);

    dim3 eblk(256), egrid(EE / 32, DD / 128);
    dim3 gblk(256), ggrid((NN + 63) / 64, DD / 128);

    for (int l = 0; l < LLAYERS; l++) {
        hipMemsetAsync(agg, 0, (size_t)NN * DD * sizeof(float), stream);
        edge_kernel<<<egrid, eblk, 0, stream>>>(
            h, edge_attr, We + (size_t)l * EDIM * DD, be + (size_t)l * DD,
            ssrc, sdst, perm, agg);
        axpb_kernel<<<dim3(NN * DD / 4 / 256), 256, 0, stream>>>(h, agg, eps + l, g);
        gemm_kernel<true><<<ggrid, gblk, 0, stream>>>(
            g, W1 + (size_t)l * DD * DD, b1 + (size_t)l * DD, agg /*t1*/, NN);
        gemm_kernel<false><<<ggrid, gblk, 0, stream>>>(
            agg, W2 + (size_t)l * DD * DD, b2 + (size_t)l * DD, g, NN);
        relu_ln_kernel<<<dim3(NN), 256, 0, stream>>>(
            g, gamma + (size_t)l * DD, beta + (size_t)l * DD, h);
    }
    gemm_kernel<false><<<ggrid, gblk, 0, stream>>>(h, Wf, bf, (float*)d_out, NN);
}

// Round 4
// 1144.116 us; speedup vs baseline: 4.4257x; 3.3175x over previous
//
#include <hip/hip_runtime.h>

#define NN 10000
#define EE 160000
#define DD 512
#define EDIM 128
#define LLAYERS 3
#define LN_EPS 1e-5f

typedef __attribute__((ext_vector_type(8))) short bf16x8;
typedef __attribute__((ext_vector_type(4))) float f32x4;

__device__ __forceinline__ unsigned short f2b(float f) {
    union { float f; unsigned u; } v; v.f = f;
    unsigned r = (v.u + 0x7fffu + ((v.u >> 16) & 1u)) >> 16;
    return (unsigned short)r;
}
__device__ __forceinline__ float b2f(unsigned short s) {
    union { unsigned u; float f; } v; v.u = ((unsigned)s) << 16;
    return v.f;
}

// ---------------- CSR build: counting sort of edges by dst ----------------
__global__ __launch_bounds__(256) void hist_kernel(
    const int* __restrict__ dstv, int* __restrict__ deg)
{
    int e = blockIdx.x * 256 + threadIdx.x;
    if (e < EE) atomicAdd(&deg[dstv[e]], 1);
}

__global__ __launch_bounds__(256) void scan_kernel(
    const int* __restrict__ deg, int* __restrict__ base, int* __restrict__ cursor)
{
    __shared__ int sums[256];
    const int t = threadIdx.x;
    const int CH = 40;                       // 256*40 = 10240 >= NN
    int lo = t * CH;
    int hi = lo + CH; if (hi > NN) hi = NN;
    int s = 0;
    for (int i = lo; i < hi; i++) s += deg[i];
    sums[t] = s;
    __syncthreads();
    for (int off = 1; off < 256; off <<= 1) {
        int v = (t >= off) ? sums[t - off] : 0;
        __syncthreads();
        sums[t] += v;
        __syncthreads();
    }
    int run = (t == 0) ? 0 : sums[t - 1];
    for (int i = lo; i < hi; i++) {
        base[i] = run; cursor[i] = run;
        run += deg[i];
    }
}

__global__ __launch_bounds__(256) void scatter_kernel(
    const int* __restrict__ srcv, const int* __restrict__ dstv,
    int* __restrict__ cursor,
    int* __restrict__ ssrc, int* __restrict__ sdst, int* __restrict__ perm)
{
    int e = blockIdx.x * 256 + threadIdx.x;
    if (e < EE) {
        int d = dstv[e];
        int pos = atomicAdd(&cursor[d], 1);
        ssrc[pos] = srcv[e];
        sdst[pos] = d;
        perm[pos] = e;
    }
}

// ---------------- fp32 -> bf16 transpose (src[K][N] -> dst[N][K]) ----------------
__global__ __launch_bounds__(256) void transpose_bf16_kernel(
    const float* __restrict__ src, unsigned short* __restrict__ dst, int K, int N)
{
    __shared__ float t[32][33];
    const int x = threadIdx.x & 31;
    const int y = threadIdx.x >> 5;          // 0..7
    const int bn = blockIdx.x * 32;
    const int bk = blockIdx.y * 32;
    #pragma unroll
    for (int j = 0; j < 32; j += 8)
        t[y + j][x] = src[(size_t)(bk + y + j) * N + bn + x];
    __syncthreads();
    #pragma unroll
    for (int j = 0; j < 32; j += 8)
        dst[(size_t)(bn + y + j) * K + bk + x] = f2b(t[x][y + j]);
}

// ---------------- fp32 -> bf16 elementwise convert (4 elems/thread) ----------------
__global__ __launch_bounds__(256) void cvt_bf16_kernel(
    const float* __restrict__ src, unsigned short* __restrict__ dst)
{
    int i = blockIdx.x * 256 + threadIdx.x;
    float4 v = ((const float4*)src)[i];
    uint2 o;
    o.x = (unsigned)f2b(v.x) | ((unsigned)f2b(v.y) << 16);
    o.y = (unsigned)f2b(v.z) | ((unsigned)f2b(v.w) << 16);
    ((uint2*)dst)[i] = o;
}

// ---------------- edge kernel (MFMA, dst-sorted) ----------------
// Block: 64 edges x 128 cols, K = EDIM = 128. 4 waves: wave w -> edge-half
// (w&1)*32, col-slab (w>>1)*64. A-frags read from global fp32 (cvt to bf16),
// B = WeT[n][k] bf16 staged in LDS. Epilogue: h[src] add, relu, run-combined
// fp32 atomics into agg[dst].
#define EPITCH 136   // 128 + 8 bf16 pad: bank stride 68 dw -> 2-way (free)
__global__ __launch_bounds__(256) void edge_kernel(
    const unsigned short* __restrict__ h_bf,
    const float* __restrict__ edge_attr,
    const unsigned short* __restrict__ WeT,   // [512 n][128 k] bf16 (layer slice)
    const float* __restrict__ be,             // [512] fp32
    const int* __restrict__ ssrc,
    const int* __restrict__ sdst,
    const int* __restrict__ perm,
    float* __restrict__ agg)
{
    __shared__ unsigned short sB[128 * EPITCH];   // 34.8 KB

    const int tid  = threadIdx.x;
    const int e0   = blockIdx.x * 64;
    const int c0   = blockIdx.y * 128;
    const int w    = tid >> 6;
    const int lane = tid & 63;
    const int quad = lane >> 4;
    const int l16  = lane & 15;
    const int mh   = (w & 1) * 32;
    const int nsl  = (w >> 1) * 64;

    // stage WeT tile: 128 n-rows x full K=128, 16B chunks
    for (int i = tid; i < 128 * 16; i += 256) {
        int n = i >> 4, seg = i & 15;
        *(uint4*)&sB[n * EPITCH + seg * 8] =
            *(const uint4*)&WeT[(size_t)(c0 + n) * EDIM + seg * 8];
    }

    const int prow0 = perm[e0 + mh + l16];
    const int prow1 = perm[e0 + mh + 16 + l16];
    const float* ar0 = edge_attr + (size_t)prow0 * EDIM;
    const float* ar1 = edge_attr + (size_t)prow1 * EDIM;

    f32x4 acc[2][4];
    #pragma unroll
    for (int mr = 0; mr < 2; mr++)
        #pragma unroll
        for (int nb = 0; nb < 4; nb++)
            acc[mr][nb] = (f32x4){0.f, 0.f, 0.f, 0.f};

    __syncthreads();

    #pragma unroll
    for (int ks = 0; ks < 4; ks++) {
        const int ko = ks * 32 + quad * 8;
        float4 x0 = *(const float4*)(ar0 + ko);
        float4 x1 = *(const float4*)(ar0 + ko + 4);
        float4 y0 = *(const float4*)(ar1 + ko);
        float4 y1 = *(const float4*)(ar1 + ko + 4);
        bf16x8 a0, a1;
        a0[0]=(short)f2b(x0.x); a0[1]=(short)f2b(x0.y); a0[2]=(short)f2b(x0.z); a0[3]=(short)f2b(x0.w);
        a0[4]=(short)f2b(x1.x); a0[5]=(short)f2b(x1.y); a0[6]=(short)f2b(x1.z); a0[7]=(short)f2b(x1.w);
        a1[0]=(short)f2b(y0.x); a1[1]=(short)f2b(y0.y); a1[2]=(short)f2b(y0.z); a1[3]=(short)f2b(y0.w);
        a1[4]=(short)f2b(y1.x); a1[5]=(short)f2b(y1.y); a1[6]=(short)f2b(y1.z); a1[7]=(short)f2b(y1.w);

        bf16x8 b[4];
        #pragma unroll
        for (int nb = 0; nb < 4; nb++)
            b[nb] = *(const bf16x8*)&sB[(nsl + nb * 16 + l16) * EPITCH + ko];

        #pragma unroll
        for (int nb = 0; nb < 4; nb++) {
            acc[0][nb] = __builtin_amdgcn_mfma_f32_16x16x32_bf16(a0, b[nb], acc[0][nb], 0, 0, 0);
            acc[1][nb] = __builtin_amdgcn_mfma_f32_16x16x32_bf16(a1, b[nb], acc[1][nb], 0, 0, 0);
        }
    }

    // epilogue: C/D layout col=l16, row=quad*4+reg -> 4 consecutive sorted edges
    #pragma unroll
    for (int mr = 0; mr < 2; mr++) {
        const int ebase = e0 + mh + mr * 16 + quad * 4;
        const int s0 = ssrc[ebase],     d0 = sdst[ebase];
        const int s1 = ssrc[ebase + 1], d1 = sdst[ebase + 1];
        const int s2 = ssrc[ebase + 2], d2 = sdst[ebase + 2];
        const int s3 = ssrc[ebase + 3], d3 = sdst[ebase + 3];
        #pragma unroll
        for (int nb = 0; nb < 4; nb++) {
            const int c = c0 + nsl + nb * 16 + l16;
            const float bias = be[c];
            const f32x4 v = acc[mr][nb];
            float m0 = fmaxf(v[0] + bias + b2f(h_bf[(size_t)s0 * DD + c]), 0.f);
            float m1 = fmaxf(v[1] + bias + b2f(h_bf[(size_t)s1 * DD + c]), 0.f);
            float m2 = fmaxf(v[2] + bias + b2f(h_bf[(size_t)s2 * DD + c]), 0.f);
            float m3 = fmaxf(v[3] + bias + b2f(h_bf[(size_t)s3 * DD + c]), 0.f);
            float run = m0; int rd = d0;
            if (d1 == rd) run += m1; else { atomicAdd(&agg[(size_t)rd * DD + c], run); run = m1; rd = d1; }
            if (d2 == rd) run += m2; else { atomicAdd(&agg[(size_t)rd * DD + c], run); run = m2; rd = d2; }
            if (d3 == rd) run += m3; else { atomicAdd(&agg[(size_t)rd * DD + c], run); run = m3; rd = d3; }
            atomicAdd(&agg[(size_t)rd * DD + c], run);
        }
    }
}

// ---------------- node GEMM (MFMA bf16) ----------------
// C[M,512] = act(A[M,512] @ W[512,512] + bias); W given as WT[n][k] bf16.
// Block 64m x 128n, K-chunks of 128; 4 waves each 32m x 64n.
#define GPITCH 136
template <bool RELU, bool OUTBF>
__global__ __launch_bounds__(256) void mfma_gemm(
    const unsigned short* __restrict__ A,    // [M][512] bf16
    const unsigned short* __restrict__ WT,   // [512 n][512 k] bf16
    const float* __restrict__ bias,          // [512] fp32
    void* __restrict__ Cout, int M)
{
    __shared__ unsigned short sA[64 * GPITCH];    // 17.4 KB
    __shared__ unsigned short sB[128 * GPITCH];   // 34.8 KB

    const int tid  = threadIdx.x;
    const int m0   = blockIdx.x * 64;
    const int c0   = blockIdx.y * 128;
    const int w    = tid >> 6;
    const int lane = tid & 63;
    const int quad = lane >> 4;
    const int l16  = lane & 15;
    const int mh   = (w & 1) * 32;
    const int nsl  = (w >> 1) * 64;

    f32x4 acc[2][4];
    #pragma unroll
    for (int mr = 0; mr < 2; mr++)
        #pragma unroll
        for (int nb = 0; nb < 4; nb++)
            acc[mr][nb] = (f32x4){0.f, 0.f, 0.f, 0.f};

    for (int kc = 0; kc < DD; kc += 128) {
        __syncthreads();
        for (int i = tid; i < 64 * 16; i += 256) {   // A: 64 rows x 16 segs
            int r = i >> 4, seg = i & 15;
            int gm = m0 + r;
            uint4 v = make_uint4(0u, 0u, 0u, 0u);
            if (gm < M) v = *(const uint4*)&A[(size_t)gm * DD + kc + seg * 8];
            *(uint4*)&sA[r * GPITCH + seg * 8] = v;
        }
        for (int i = tid; i < 128 * 16; i += 256) {  // B: 128 rows x 16 segs
            int r = i >> 4, seg = i & 15;
            *(uint4*)&sB[r * GPITCH + seg * 8] =
                *(const uint4*)&WT[(size_t)(c0 + r) * DD + kc + seg * 8];
        }
        __syncthreads();
        #pragma unroll
        for (int ks = 0; ks < 4; ks++) {
            const int ko = ks * 32 + quad * 8;
            bf16x8 a0 = *(const bf16x8*)&sA[(mh + l16) * GPITCH + ko];
            bf16x8 a1 = *(const bf16x8*)&sA[(mh + 16 + l16) * GPITCH + ko];
            bf16x8 b[4];
            #pragma unroll
            for (int nb = 0; nb < 4; nb++)
                b[nb] = *(const bf16x8*)&sB[(nsl + nb * 16 + l16) * GPITCH + ko];
            #pragma unroll
            for (int nb = 0; nb < 4; nb++) {
                acc[0][nb] = __builtin_amdgcn_mfma_f32_16x16x32_bf16(a0, b[nb], acc[0][nb], 0, 0, 0);
                acc[1][nb] = __builtin_amdgcn_mfma_f32_16x16x32_bf16(a1, b[nb], acc[1][nb], 0, 0, 0);
            }
        }
    }

    #pragma unroll
    for (int mr = 0; mr < 2; mr++) {
        const int rbase = m0 + mh + mr * 16 + quad * 4;
        #pragma unroll
        for (int nb = 0; nb < 4; nb++) {
            const int c = c0 + nsl + nb * 16 + l16;
            const float bv = bias[c];
            const f32x4 v = acc[mr][nb];
            #pragma unroll
            for (int reg = 0; reg < 4; reg++) {
                int gm = rbase + reg;
                if (gm < M) {
                    float val = v[reg] + bv;
                    if (RELU) val = fmaxf(val, 0.f);
                    if (OUTBF) ((unsigned short*)Cout)[(size_t)gm * DD + c] = f2b(val);
                    else       ((float*)Cout)[(size_t)gm * DD + c] = val;
                }
            }
        }
    }
}

// ---------------- g = (1+eps)*h + agg  (bf16 h in, bf16 g out) ----------------
__global__ __launch_bounds__(256) void axpb_kernel(
    const unsigned short* __restrict__ h_bf, const float* __restrict__ agg,
    const float* __restrict__ eps_p, unsigned short* __restrict__ g_bf)
{
    int i = blockIdx.x * 256 + threadIdx.x;   // per 4 elems
    float s = 1.0f + eps_p[0];
    uint2 hv = ((const uint2*)h_bf)[i];
    float4 av = ((const float4*)agg)[i];
    float h0 = b2f((unsigned short)(hv.x & 0xffff));
    float h1 = b2f((unsigned short)(hv.x >> 16));
    float h2 = b2f((unsigned short)(hv.y & 0xffff));
    float h3 = b2f((unsigned short)(hv.y >> 16));
    uint2 o;
    o.x = (unsigned)f2b(s * h0 + av.x) | ((unsigned)f2b(s * h1 + av.y) << 16);
    o.y = (unsigned)f2b(s * h2 + av.z) | ((unsigned)f2b(s * h3 + av.w) << 16);
    ((uint2*)g_bf)[i] = o;
}

// ---------------- fused ReLU + LayerNorm (bf16 in/out, fp32 stats) ----------------
__global__ __launch_bounds__(256) void relu_ln_kernel(
    const unsigned short* __restrict__ g2,
    const float* __restrict__ gamma,
    const float* __restrict__ beta,
    unsigned short* __restrict__ hout)
{
    __shared__ float ss[4], ssq[4];
    const int row = blockIdx.x;
    const int tid = threadIdx.x;
    const unsigned short* gr = g2 + (size_t)row * DD;

    float v0 = fmaxf(b2f(gr[tid]), 0.f);
    float v1 = fmaxf(b2f(gr[tid + 256]), 0.f);
    float s  = v0 + v1;
    float sq = v0 * v0 + v1 * v1;
    #pragma unroll
    for (int off = 32; off > 0; off >>= 1) {
        s  += __shfl_down(s, off);
        sq += __shfl_down(sq, off);
    }
    const int wave = tid >> 6;
    const int lane = tid & 63;
    if (lane == 0) { ss[wave] = s; ssq[wave] = sq; }
    __syncthreads();
    if (tid == 0) {
        float S  = ss[0] + ss[1] + ss[2] + ss[3];
        float SQ = ssq[0] + ssq[1] + ssq[2] + ssq[3];
        float mu = S * (1.f / 512.f);
        float var = SQ * (1.f / 512.f) - mu * mu;
        ss[0]  = mu;
        ssq[0] = rsqrtf(var + LN_EPS);
    }
    __syncthreads();
    float mu = ss[0], rstd = ssq[0];
    hout[(size_t)row * DD + tid] =
        f2b((v0 - mu) * rstd * gamma[tid] + beta[tid]);
    hout[(size_t)row * DD + tid + 256] =
        f2b((v1 - mu) * rstd * gamma[tid + 256] + beta[tid + 256]);
}

extern "C" void kernel_launch(void* const* d_in, const int* in_sizes, int n_in,
                              void* d_out, int out_size, void* d_ws, size_t ws_size,
                              hipStream_t stream)
{
    (void)in_sizes; (void)n_in; (void)out_size; (void)ws_size;

    const float* x          = (const float*)d_in[0];
    const int*   edge_index = (const int*)d_in[1];   // int32 per harness contract
    const float* edge_attr  = (const float*)d_in[2];
    const float* We         = (const float*)d_in[3];
    const float* be         = (const float*)d_in[4];
    const float* eps        = (const float*)d_in[5];
    const float* W1         = (const float*)d_in[6];
    const float* b1         = (const float*)d_in[7];
    const float* W2         = (const float*)d_in[8];
    const float* b2         = (const float*)d_in[9];
    const float* gamma      = (const float*)d_in[10];
    const float* beta       = (const float*)d_in[11];
    const float* Wf         = (const float*)d_in[12];
    const float* bf         = (const float*)d_in[13];

    // ---- workspace layout (~47 MB) ----
    float*          agg  = (float*)d_ws;                           // [N*512] f32
    unsigned short* t1   = (unsigned short*)agg;                   // alias: used after agg consumed
    unsigned short* h_bf = (unsigned short*)(agg + (size_t)NN*DD); // [N*512]
    unsigned short* g_bf = h_bf + (size_t)NN * DD;                 // [N*512]
    unsigned short* WeT  = g_bf + (size_t)NN * DD;                 // [3][512][128]
    unsigned short* W1T  = WeT + (size_t)3 * DD * EDIM;            // [3][512][512]
    unsigned short* W2T  = W1T + (size_t)3 * DD * DD;
    unsigned short* WfT  = W2T + (size_t)3 * DD * DD;              // [512][512]
    int* deg    = (int*)(WfT + (size_t)DD * DD);
    int* base   = deg + NN;
    int* cursor = base + NN;
    int* ssrc   = cursor + NN;
    int* sdst   = ssrc + EE;
    int* perm   = sdst + EE;

    const int* srcv = edge_index;
    const int* dstv = edge_index + EE;

    // ---- prepass: sort, converts, transposes (cheap; once per launch) ----
    hipMemsetAsync(deg, 0, NN * sizeof(int), stream);
    hist_kernel<<<dim3((EE + 255) / 256), 256, 0, stream>>>(dstv, deg);
    scan_kernel<<<dim3(1), 256, 0, stream>>>(deg, base, cursor);
    scatter_kernel<<<dim3((EE + 255) / 256), 256, 0, stream>>>(
        srcv, dstv, cursor, ssrc, sdst, perm);

    cvt_bf16_kernel<<<dim3(NN * DD / 4 / 256), 256, 0, stream>>>(x, h_bf);
    for (int l = 0; l < LLAYERS; l++) {
        transpose_bf16_kernel<<<dim3(DD / 32, EDIM / 32), 256, 0, stream>>>(
            We + (size_t)l * EDIM * DD, WeT + (size_t)l * DD * EDIM, EDIM, DD);
        transpose_bf16_kernel<<<dim3(DD / 32, DD / 32), 256, 0, stream>>>(
            W1 + (size_t)l * DD * DD, W1T + (size_t)l * DD * DD, DD, DD);
        transpose_bf16_kernel<<<dim3(DD / 32, DD / 32), 256, 0, stream>>>(
            W2 + (size_t)l * DD * DD, W2T + (size_t)l * DD * DD, DD, DD);
    }
    transpose_bf16_kernel<<<dim3(DD / 32, DD / 32), 256, 0, stream>>>(Wf, WfT, DD, DD);

    dim3 eblk(256), egrid(EE / 64, DD / 128);
    dim3 gblk(256), ggrid((NN + 63) / 64, DD / 128);

    for (int l = 0; l < LLAYERS; l++) {
        hipMemsetAsync(agg, 0, (size_t)NN * DD * sizeof(float), stream);
        edge_kernel<<<egrid, eblk, 0, stream>>>(
            h_bf, edge_attr, WeT + (size_t)l * DD * EDIM, be + (size_t)l * DD,
            ssrc, sdst, perm, agg);
        axpb_kernel<<<dim3(NN * DD / 4 / 256), 256, 0, stream>>>(h_bf, agg, eps + l, g_bf);
        mfma_gemm<true, true><<<ggrid, gblk, 0, stream>>>(
            g_bf, W1T + (size_t)l * DD * DD, b1 + (size_t)l * DD, t1, NN);
        mfma_gemm<false, true><<<ggrid, gblk, 0, stream>>>(
            t1, W2T + (size_t)l * DD * DD, b2 + (size_t)l * DD, g_bf, NN);
        relu_ln_kernel<<<dim3(NN), 256, 0, stream>>>(
            g_bf, gamma + (size_t)l * DD, beta + (size_t)l * DD, h_bf);
    }
    mfma_gemm<false, false><<<ggrid, gblk, 0, stream>>>(h_bf, WfT, bf, d_out, NN);
}

// Round 5
// 1065.316 us; speedup vs baseline: 4.7530x; 1.0740x over previous
//
#include <hip/hip_runtime.h>

#define NN 10000
#define EE 160000
#define DD 512
#define EDIM 128
#define LLAYERS 3
#define LN_EPS 1e-5f

typedef __attribute__((ext_vector_type(8))) short bf16x8;
typedef __attribute__((ext_vector_type(4))) float f32x4;

__device__ __forceinline__ unsigned short f2b(float f) {
    union { float f; unsigned u; } v; v.f = f;
    unsigned r = (v.u + 0x7fffu + ((v.u >> 16) & 1u)) >> 16;
    return (unsigned short)r;
}
__device__ __forceinline__ float b2f(unsigned short s) {
    union { unsigned u; float f; } v; v.u = ((unsigned)s) << 16;
    return v.f;
}

// ---------------- CSR build: counting sort of edges by dst ----------------
__global__ __launch_bounds__(256) void hist_kernel(
    const int* __restrict__ dstv, int* __restrict__ deg)
{
    int e = blockIdx.x * 256 + threadIdx.x;
    if (e < EE) atomicAdd(&deg[dstv[e]], 1);
}

__global__ __launch_bounds__(256) void scan_kernel(
    const int* __restrict__ deg, int* __restrict__ base, int* __restrict__ cursor)
{
    __shared__ int sums[256];
    const int t = threadIdx.x;
    const int CH = 40;                       // 256*40 = 10240 >= NN
    int lo = t * CH;
    int hi = lo + CH; if (hi > NN) hi = NN;
    int s = 0;
    for (int i = lo; i < hi; i++) s += deg[i];
    sums[t] = s;
    __syncthreads();
    for (int off = 1; off < 256; off <<= 1) {
        int v = (t >= off) ? sums[t - off] : 0;
        __syncthreads();
        sums[t] += v;
        __syncthreads();
    }
    int run = (t == 0) ? 0 : sums[t - 1];
    for (int i = lo; i < hi; i++) {
        base[i] = run; cursor[i] = run;
        run += deg[i];
    }
}

__global__ __launch_bounds__(256) void scatter_kernel(
    const int* __restrict__ srcv, const int* __restrict__ dstv,
    int* __restrict__ cursor,
    int* __restrict__ ssrc, int* __restrict__ sdst, int* __restrict__ perm)
{
    int e = blockIdx.x * 256 + threadIdx.x;
    if (e < EE) {
        int d = dstv[e];
        int pos = atomicAdd(&cursor[d], 1);
        ssrc[pos] = srcv[e];
        sdst[pos] = d;
        perm[pos] = e;
    }
}

// ---------------- fp32 -> bf16 transpose (src[K][N] -> dst[N][K]) ----------------
__global__ __launch_bounds__(256) void transpose_bf16_kernel(
    const float* __restrict__ src, unsigned short* __restrict__ dst, int K, int N)
{
    __shared__ float t[32][33];
    const int x = threadIdx.x & 31;
    const int y = threadIdx.x >> 5;          // 0..7
    const int bn = blockIdx.x * 32;
    const int bk = blockIdx.y * 32;
    #pragma unroll
    for (int j = 0; j < 32; j += 8)
        t[y + j][x] = src[(size_t)(bk + y + j) * N + bn + x];
    __syncthreads();
    #pragma unroll
    for (int j = 0; j < 32; j += 8)
        dst[(size_t)(bn + y + j) * K + bk + x] = f2b(t[x][y + j]);
}

// ---------------- fp32 -> bf16 elementwise convert (4 elems/thread) ----------------
__global__ __launch_bounds__(256) void cvt_bf16_kernel(
    const float* __restrict__ src, unsigned short* __restrict__ dst)
{
    int i = blockIdx.x * 256 + threadIdx.x;
    float4 v = ((const float4*)src)[i];
    uint2 o;
    o.x = (unsigned)f2b(v.x) | ((unsigned)f2b(v.y) << 16);
    o.y = (unsigned)f2b(v.z) | ((unsigned)f2b(v.w) << 16);
    ((uint2*)dst)[i] = o;
}

// ---------------- edge kernel (MFMA, dst-sorted, LDS-aggregated) ----------------
// Block: 64 edges x 128 cols, K = EDIM = 128. 4 waves: wave w -> edge-half
// (w&1)*32, col-slab (w>>1)*64.
// A: perm-gathered edge_attr (fp32->bf16) staged in LDS.
// B: WeT[n][k] bf16 read directly from global (128KB slice, L2-resident).
// Epilogue: h[src] add + relu; accumulate into LDS sAgg (dsts span ~5 rows
// for sorted edges), then one global-atomic flush per distinct dst row.
#define EP 136     // A pitch: 128+8 bf16 -> 2-way bank alias (free)
#define AP 132     // sAgg pitch in floats
__global__ __launch_bounds__(256) void edge_kernel(
    const unsigned short* __restrict__ h_bf,
    const float* __restrict__ edge_attr,
    const unsigned short* __restrict__ WeT,   // [512 n][128 k] bf16 (layer slice)
    const float* __restrict__ be,             // [512] fp32
    const int* __restrict__ ssrc,
    const int* __restrict__ sdst,
    const int* __restrict__ perm,
    float* __restrict__ agg)
{
    __shared__ unsigned short sA[64 * EP];    // 17.4 KB
    __shared__ float sAgg[64 * AP];           // 33.8 KB

    const int tid  = threadIdx.x;
    const int e0   = blockIdx.x * 64;
    const int c0   = blockIdx.y * 128;
    const int w    = tid >> 6;
    const int lane = tid & 63;
    const int quad = lane >> 4;
    const int l16  = lane & 15;
    const int mh   = (w & 1) * 32;
    const int nsl  = (w >> 1) * 64;

    // stage A: 64 edges x 16 segs of 8 fp32 -> 8 bf16 (perm gather)
    for (int i = tid; i < 64 * 16; i += 256) {
        int e = i >> 4, seg = i & 15;
        const float* p = edge_attr + (size_t)perm[e0 + e] * EDIM + seg * 8;
        float4 u = *(const float4*)p;
        float4 v = *(const float4*)(p + 4);
        uint4 o;
        o.x = (unsigned)f2b(u.x) | ((unsigned)f2b(u.y) << 16);
        o.y = (unsigned)f2b(u.z) | ((unsigned)f2b(u.w) << 16);
        o.z = (unsigned)f2b(v.x) | ((unsigned)f2b(v.y) << 16);
        o.w = (unsigned)f2b(v.z) | ((unsigned)f2b(v.w) << 16);
        *(uint4*)&sA[e * EP + seg * 8] = o;
    }
    // zero sAgg (64*132 = 8448 floats = 2112 f32x4)
    for (int i = tid; i < 64 * AP / 4; i += 256)
        ((f32x4*)sAgg)[i] = (f32x4){0.f, 0.f, 0.f, 0.f};

    __syncthreads();

    f32x4 acc[2][4];
    #pragma unroll
    for (int mr = 0; mr < 2; mr++)
        #pragma unroll
        for (int nb = 0; nb < 4; nb++)
            acc[mr][nb] = (f32x4){0.f, 0.f, 0.f, 0.f};

    #pragma unroll
    for (int ks = 0; ks < 4; ks++) {
        const int ko = ks * 32 + quad * 8;
        bf16x8 a0 = *(const bf16x8*)&sA[(mh + l16) * EP + ko];
        bf16x8 a1 = *(const bf16x8*)&sA[(mh + 16 + l16) * EP + ko];
        bf16x8 b[4];
        #pragma unroll
        for (int nb = 0; nb < 4; nb++)
            b[nb] = *(const bf16x8*)&WeT[(size_t)(c0 + nsl + nb * 16 + l16) * EDIM + ko];
        #pragma unroll
        for (int nb = 0; nb < 4; nb++) {
            acc[0][nb] = __builtin_amdgcn_mfma_f32_16x16x32_bf16(a0, b[nb], acc[0][nb], 0, 0, 0);
            acc[1][nb] = __builtin_amdgcn_mfma_f32_16x16x32_bf16(a1, b[nb], acc[1][nb], 0, 0, 0);
        }
    }

    // epilogue: run-combine 4 consecutive sorted edges, accumulate into sAgg
    const int dbase = sdst[e0];
    #pragma unroll
    for (int mr = 0; mr < 2; mr++) {
        const int ebase = e0 + mh + mr * 16 + quad * 4;
        const int s0 = ssrc[ebase],     d0 = sdst[ebase];
        const int s1 = ssrc[ebase + 1], d1 = sdst[ebase + 1];
        const int s2 = ssrc[ebase + 2], d2 = sdst[ebase + 2];
        const int s3 = ssrc[ebase + 3], d3 = sdst[ebase + 3];
        #pragma unroll
        for (int nb = 0; nb < 4; nb++) {
            const int c  = nsl + nb * 16 + l16;   // block-local col
            const int gc = c0 + c;
            const float bias = be[gc];
            const f32x4 v = acc[mr][nb];
            float m0 = fmaxf(v[0] + bias + b2f(h_bf[(size_t)s0 * DD + gc]), 0.f);
            float m1 = fmaxf(v[1] + bias + b2f(h_bf[(size_t)s1 * DD + gc]), 0.f);
            float m2 = fmaxf(v[2] + bias + b2f(h_bf[(size_t)s2 * DD + gc]), 0.f);
            float m3 = fmaxf(v[3] + bias + b2f(h_bf[(size_t)s3 * DD + gc]), 0.f);
            float run = m0; int rd = d0;
            #define FLUSH_RUN()                                            \
                do {                                                       \
                    int ld = rd - dbase;                                   \
                    if ((unsigned)ld < 64u)                                \
                        atomicAdd(&sAgg[ld * AP + c], run);                \
                    else                                                   \
                        atomicAdd(&agg[(size_t)rd * DD + gc], run);        \
                } while (0)
            if (d1 == rd) run += m1; else { FLUSH_RUN(); run = m1; rd = d1; }
            if (d2 == rd) run += m2; else { FLUSH_RUN(); run = m2; rd = d2; }
            if (d3 == rd) run += m3; else { FLUSH_RUN(); run = m3; rd = d3; }
            FLUSH_RUN();
            #undef FLUSH_RUN
        }
    }

    __syncthreads();

    // flush distinct dst rows once
    int nloc = sdst[e0 + 63] - dbase + 1;
    if (nloc > 64) nloc = 64;
    for (int i = tid; i < nloc * 128; i += 256) {
        int r = i >> 7, c = i & 127;
        float v = sAgg[r * AP + c];
        if (v != 0.f) atomicAdd(&agg[(size_t)(dbase + r) * DD + c0 + c], v);
    }
}

// ---------------- node GEMM (MFMA bf16), optional fused (1+eps)*h + agg ----------------
// C[M,512] = act(A'[M,512] @ W[512,512] + bias); W given as WT[n][k] bf16.
// A' = FUSE ? (1+eps)*A + agg : A. Block 64m x 128n, K-chunks of 128.
#define GPITCH 136
template <bool FUSE, bool RELU, bool OUTBF>
__global__ __launch_bounds__(256) void mfma_gemm(
    const unsigned short* __restrict__ A,    // [M][512] bf16
    const float* __restrict__ aggp,          // [M][512] fp32 (FUSE only)
    const float* __restrict__ epsp,          // scalar (FUSE only)
    const unsigned short* __restrict__ WT,   // [512 n][512 k] bf16
    const float* __restrict__ bias,          // [512] fp32
    void* __restrict__ Cout, int M)
{
    __shared__ unsigned short sA[64 * GPITCH];    // 17.4 KB
    __shared__ unsigned short sB[128 * GPITCH];   // 34.8 KB

    const int tid  = threadIdx.x;
    const int m0   = blockIdx.x * 64;
    const int c0   = blockIdx.y * 128;
    const int w    = tid >> 6;
    const int lane = tid & 63;
    const int quad = lane >> 4;
    const int l16  = lane & 15;
    const int mh   = (w & 1) * 32;
    const int nsl  = (w >> 1) * 64;

    const float es = FUSE ? (1.0f + epsp[0]) : 0.0f;

    f32x4 acc[2][4];
    #pragma unroll
    for (int mr = 0; mr < 2; mr++)
        #pragma unroll
        for (int nb = 0; nb < 4; nb++)
            acc[mr][nb] = (f32x4){0.f, 0.f, 0.f, 0.f};

    for (int kc = 0; kc < DD; kc += 128) {
        __syncthreads();
        for (int i = tid; i < 64 * 16; i += 256) {   // A: 64 rows x 16 segs
            int r = i >> 4, seg = i & 15;
            int gm = m0 + r;
            uint4 v = make_uint4(0u, 0u, 0u, 0u);
            if (gm < M) {
                v = *(const uint4*)&A[(size_t)gm * DD + kc + seg * 8];
                if (FUSE) {
                    const float* ap = aggp + (size_t)gm * DD + kc + seg * 8;
                    float4 g0 = *(const float4*)ap;
                    float4 g1 = *(const float4*)(ap + 4);
                    uint4 o;
                    o.x = (unsigned)f2b(es * b2f((unsigned short)(v.x & 0xffff)) + g0.x)
                        | ((unsigned)f2b(es * b2f((unsigned short)(v.x >> 16)) + g0.y) << 16);
                    o.y = (unsigned)f2b(es * b2f((unsigned short)(v.y & 0xffff)) + g0.z)
                        | ((unsigned)f2b(es * b2f((unsigned short)(v.y >> 16)) + g0.w) << 16);
                    o.z = (unsigned)f2b(es * b2f((unsigned short)(v.z & 0xffff)) + g1.x)
                        | ((unsigned)f2b(es * b2f((unsigned short)(v.z >> 16)) + g1.y) << 16);
                    o.w = (unsigned)f2b(es * b2f((unsigned short)(v.w & 0xffff)) + g1.z)
                        | ((unsigned)f2b(es * b2f((unsigned short)(v.w >> 16)) + g1.w) << 16);
                    v = o;
                }
            }
            *(uint4*)&sA[r * GPITCH + seg * 8] = v;
        }
        for (int i = tid; i < 128 * 16; i += 256) {  // B: 128 rows x 16 segs
            int r = i >> 4, seg = i & 15;
            *(uint4*)&sB[r * GPITCH + seg * 8] =
                *(const uint4*)&WT[(size_t)(c0 + r) * DD + kc + seg * 8];
        }
        __syncthreads();
        #pragma unroll
        for (int ks = 0; ks < 4; ks++) {
            const int ko = ks * 32 + quad * 8;
            bf16x8 a0 = *(const bf16x8*)&sA[(mh + l16) * GPITCH + ko];
            bf16x8 a1 = *(const bf16x8*)&sA[(mh + 16 + l16) * GPITCH + ko];
            bf16x8 b[4];
            #pragma unroll
            for (int nb = 0; nb < 4; nb++)
                b[nb] = *(const bf16x8*)&sB[(nsl + nb * 16 + l16) * GPITCH + ko];
            #pragma unroll
            for (int nb = 0; nb < 4; nb++) {
                acc[0][nb] = __builtin_amdgcn_mfma_f32_16x16x32_bf16(a0, b[nb], acc[0][nb], 0, 0, 0);
                acc[1][nb] = __builtin_amdgcn_mfma_f32_16x16x32_bf16(a1, b[nb], acc[1][nb], 0, 0, 0);
            }
        }
    }

    #pragma unroll
    for (int mr = 0; mr < 2; mr++) {
        const int rbase = m0 + mh + mr * 16 + quad * 4;
        #pragma unroll
        for (int nb = 0; nb < 4; nb++) {
            const int c = c0 + nsl + nb * 16 + l16;
            const float bv = bias[c];
            const f32x4 v = acc[mr][nb];
            #pragma unroll
            for (int reg = 0; reg < 4; reg++) {
                int gm = rbase + reg;
                if (gm < M) {
                    float val = v[reg] + bv;
                    if (RELU) val = fmaxf(val, 0.f);
                    if (OUTBF) ((unsigned short*)Cout)[(size_t)gm * DD + c] = f2b(val);
                    else       ((float*)Cout)[(size_t)gm * DD + c] = val;
                }
            }
        }
    }
}

// ---------------- fused ReLU + LayerNorm (bf16 in/out, fp32 stats) ----------------
__global__ __launch_bounds__(256) void relu_ln_kernel(
    const unsigned short* __restrict__ g2,
    const float* __restrict__ gamma,
    const float* __restrict__ beta,
    unsigned short* __restrict__ hout)
{
    __shared__ float ss[4], ssq[4];
    const int row = blockIdx.x;
    const int tid = threadIdx.x;
    const unsigned short* gr = g2 + (size_t)row * DD;

    float v0 = fmaxf(b2f(gr[tid]), 0.f);
    float v1 = fmaxf(b2f(gr[tid + 256]), 0.f);
    float s  = v0 + v1;
    float sq = v0 * v0 + v1 * v1;
    #pragma unroll
    for (int off = 32; off > 0; off >>= 1) {
        s  += __shfl_down(s, off);
        sq += __shfl_down(sq, off);
    }
    const int wave = tid >> 6;
    const int lane = tid & 63;
    if (lane == 0) { ss[wave] = s; ssq[wave] = sq; }
    __syncthreads();
    if (tid == 0) {
        float S  = ss[0] + ss[1] + ss[2] + ss[3];
        float SQ = ssq[0] + ssq[1] + ssq[2] + ssq[3];
        float mu = S * (1.f / 512.f);
        float var = SQ * (1.f / 512.f) - mu * mu;
        ss[0]  = mu;
        ssq[0] = rsqrtf(var + LN_EPS);
    }
    __syncthreads();
    float mu = ss[0], rstd = ssq[0];
    hout[(size_t)row * DD + tid] =
        f2b((v0 - mu) * rstd * gamma[tid] + beta[tid]);
    hout[(size_t)row * DD + tid + 256] =
        f2b((v1 - mu) * rstd * gamma[tid + 256] + beta[tid + 256]);
}

extern "C" void kernel_launch(void* const* d_in, const int* in_sizes, int n_in,
                              void* d_out, int out_size, void* d_ws, size_t ws_size,
                              hipStream_t stream)
{
    (void)in_sizes; (void)n_in; (void)out_size; (void)ws_size;

    const float* x          = (const float*)d_in[0];
    const int*   edge_index = (const int*)d_in[1];   // int32 per harness contract
    const float* edge_attr  = (const float*)d_in[2];
    const float* We         = (const float*)d_in[3];
    const float* be         = (const float*)d_in[4];
    const float* eps        = (const float*)d_in[5];
    const float* W1         = (const float*)d_in[6];
    const float* b1         = (const float*)d_in[7];
    const float* W2         = (const float*)d_in[8];
    const float* b2         = (const float*)d_in[9];
    const float* gamma      = (const float*)d_in[10];
    const float* beta       = (const float*)d_in[11];
    const float* Wf         = (const float*)d_in[12];
    const float* bf         = (const float*)d_in[13];

    // ---- workspace layout (~48 MB) ----
    float*          agg  = (float*)d_ws;                           // [N*512] f32
    unsigned short* t2   = (unsigned short*)agg;                   // alias: gemm2 out (after agg consumed)
    unsigned short* h_bf = (unsigned short*)(agg + (size_t)NN*DD); // [N*512]
    unsigned short* t1   = h_bf + (size_t)NN * DD;                 // [N*512] (gemm1 out)
    unsigned short* WeT  = t1 + (size_t)NN * DD;                   // [3][512][128]
    unsigned short* W1T  = WeT + (size_t)3 * DD * EDIM;            // [3][512][512]
    unsigned short* W2T  = W1T + (size_t)3 * DD * DD;
    unsigned short* WfT  = W2T + (size_t)3 * DD * DD;              // [512][512]
    int* deg    = (int*)(WfT + (size_t)DD * DD);
    int* base   = deg + NN;
    int* cursor = base + NN;
    int* ssrc   = cursor + NN;
    int* sdst   = ssrc + EE;
    int* perm   = sdst + EE;

    const int* srcv = edge_index;
    const int* dstv = edge_index + EE;

    // ---- prepass: sort, converts, transposes (cheap; once per launch) ----
    hipMemsetAsync(deg, 0, NN * sizeof(int), stream);
    hist_kernel<<<dim3((EE + 255) / 256), 256, 0, stream>>>(dstv, deg);
    scan_kernel<<<dim3(1), 256, 0, stream>>>(deg, base, cursor);
    scatter_kernel<<<dim3((EE + 255) / 256), 256, 0, stream>>>(
        srcv, dstv, cursor, ssrc, sdst, perm);

    cvt_bf16_kernel<<<dim3(NN * DD / 4 / 256), 256, 0, stream>>>(x, h_bf);
    for (int l = 0; l < LLAYERS; l++) {
        transpose_bf16_kernel<<<dim3(DD / 32, EDIM / 32), 256, 0, stream>>>(
            We + (size_t)l * EDIM * DD, WeT + (size_t)l * DD * EDIM, EDIM, DD);
        transpose_bf16_kernel<<<dim3(DD / 32, DD / 32), 256, 0, stream>>>(
            W1 + (size_t)l * DD * DD, W1T + (size_t)l * DD * DD, DD, DD);
        transpose_bf16_kernel<<<dim3(DD / 32, DD / 32), 256, 0, stream>>>(
            W2 + (size_t)l * DD * DD, W2T + (size_t)l * DD * DD, DD, DD);
    }
    transpose_bf16_kernel<<<dim3(DD / 32, DD / 32), 256, 0, stream>>>(Wf, WfT, DD, DD);

    dim3 eblk(256), egrid(EE / 64, DD / 128);
    dim3 gblk(256), ggrid((NN + 63) / 64, DD / 128);

    for (int l = 0; l < LLAYERS; l++) {
        hipMemsetAsync(agg, 0, (size_t)NN * DD * sizeof(float), stream);
        edge_kernel<<<egrid, eblk, 0, stream>>>(
            h_bf, edge_attr, WeT + (size_t)l * DD * EDIM, be + (size_t)l * DD,
            ssrc, sdst, perm, agg);
        // gemm1: A' = (1+eps)*h + agg (fused), relu, -> t1 (bf16)
        mfma_gemm<true, true, true><<<ggrid, gblk, 0, stream>>>(
            h_bf, agg, eps + l, W1T + (size_t)l * DD * DD, b1 + (size_t)l * DD, t1, NN);
        // gemm2: t1 @ W2 -> t2 (bf16, reuses agg storage)
        mfma_gemm<false, false, true><<<ggrid, gblk, 0, stream>>>(
            t1, nullptr, nullptr, W2T + (size_t)l * DD * DD, b2 + (size_t)l * DD, t2, NN);
        relu_ln_kernel<<<dim3(NN), 256, 0, stream>>>(
            t2, gamma + (size_t)l * DD, beta + (size_t)l * DD, h_bf);
    }
    mfma_gemm<false, false, false><<<ggrid, gblk, 0, stream>>>(
        h_bf, nullptr, nullptr, WfT, bf, d_out, NN);
}